// Round 10
// baseline (1849.553 us; speedup 1.0000x reference)
//
#include <hip/hip_runtime.h>
#include <stdint.h>
#include <stddef.h>

// Variational-dropout LSTM, SEQ=256, B=64, IN=H=1024, fp32 I/O.
//
// R12: protocol-stripped dataflow on R10/R11's 2-D tiling (4 rg x 64 cg).
//  (1) Sentinel dataflow: mh_seq slots 1..256 prefilled 0xFFFF (bf16 NaN,
//      unreachable from f2bf of finite h*mask). Producers fire write-through
//      u64 mh stores and stop: NO drain, NO LDS counter, NO flag. Consumers
//      poll their own 4 fragments (the poll IS the load); per-fragment
//      re-issue + backoff keeps retry volume ~8x below R9's failure mode.
//      Deletes the producer drain (~900cy) AND the flag round trip (~900cy)
//      from the inter-block chain.
//  (2) One barrier per step: lds[2][...] double buffer removes barrier #2
//      (max skew = 1 step since barrier #1 remains). Store drains migrate
//      into the next step's poll vmcnt(0), where the wave waits anyway.
// Lessons kept: no fences (R5), no cached mh (R7), don't cut block count
// (R8), bypass loads, wave-granular deps (R11).
// Fallback (small ws): R3's per-step launch path, unchanged.

#define SEQ 256

typedef __attribute__((ext_vector_type(8))) __bf16 bf16x8;
typedef __attribute__((ext_vector_type(4))) float  f32x4;
typedef __attribute__((ext_vector_type(4))) _Float16 f16x4;
typedef __attribute__((ext_vector_type(4))) unsigned int u32x4;
typedef unsigned short u16;
typedef unsigned int   u32;
typedef unsigned long long u64;

__device__ __forceinline__ u16 f2bf(float f) {
  union { float f; unsigned u; } v; v.f = f;
  unsigned r = v.u + 0x7FFFu + ((v.u >> 16) & 1u);   // RNE
  return (u16)(r >> 16);
}
__device__ __forceinline__ float sigm(float x) {
  return __builtin_amdgcn_rcpf(1.f + __expf(-x));
}
__device__ __forceinline__ float tanh_fast(float x) {
  float xc = fminf(15.f, fmaxf(-15.f, x));
  float t = __expf(-2.f * xc);
  return (1.f - t) * __builtin_amdgcn_rcpf(1.f + t);
}
__device__ __forceinline__ float pick4(int idx, float v0, float v1, float v2, float v3) {
  float lo = (idx & 1) ? v1 : v0;
  float hi = (idx & 1) ? v3 : v2;
  return (idx & 2) ? hi : lo;
}

// ws layout (bytes):
//  Wihp  @ 0         : [wb 256][kcw 32][l 64][e 8] bf16 = 8388608
//  Whhp  @ 8388608   : same = 8388608
//  Ap    @ 16777216  : [s 256][m 4][kwg 32][l 64][e 8] bf16 = 33554432
//  mh0   @ 50331648  : 131072   (fallback)
//  mh1   @ 50462720  : 131072   (fallback)
//  bias  @ 50593792  : 4096 f32 = 16384
//  c     @ 50610176  : 262144   (fallback)
//  (gap) @ 50872320  : 1024 (old flags, unused)
//  mh_seq@ 50873344  : 257 x 131072 = 33685504   (end: 84558848)

// Vectorized prep: grid 8192 x 256, each thread handles 8 contiguous u16.
__global__ __launch_bounds__(256) void prep_kernel(
    const float* __restrict__ x, const float* __restrict__ h0,
    const float* __restrict__ c0, const float* __restrict__ mask_x,
    const float* __restrict__ mask_h, const float* __restrict__ Wih,
    const float* __restrict__ Whh, const float* __restrict__ bih,
    const float* __restrict__ bhh,
    u16* __restrict__ Wihp, u16* __restrict__ Whhp, u16* __restrict__ Ap,
    u16* __restrict__ mhp0, float* __restrict__ bias, float* __restrict__ c,
    u16* __restrict__ mh_seq, int persist)
{
  const unsigned t    = blockIdx.x * 256u + threadIdx.x;  // 0 .. 2097151
  const unsigned idx8 = t * 8u;

  union Pack8 { u16 o[8]; u32x4 v; };

  // Ap[s][m][kwg][l][e0..7] = bf16( x * mask_x ), 8 contiguous k per thread
  {
    const unsigned l   = (idx8 >> 3) & 63u;
    const unsigned kwg = (idx8 >> 9) & 31u;
    const unsigned m   = (idx8 >> 14) & 3u;
    const unsigned s   = idx8 >> 16;
    const unsigned b   = m * 16u + (l & 15u);
    const unsigned k   = kwg * 32u + (l >> 4) * 8u;
    const float* xp = &x[((size_t)s * 64u + b) * 1024u + k];
    const float* mp = &mask_x[b * 1024u + k];
    Pack8 p;
    #pragma unroll
    for (int e = 0; e < 8; ++e) p.o[e] = f2bf(xp[e] * mp[e]);
    *(u32x4*)&Ap[idx8] = p.v;
  }
  // Sentinel fill of mh_seq slots 1..256 (exactly 2097152*8 u16).
  if (persist) {
    u32x4 ones = {0xFFFFFFFFu, 0xFFFFFFFFu, 0xFFFFFFFFu, 0xFFFFFFFFu};
    *(u32x4*)&mh_seq[65536u + idx8] = ones;
  }
  // W swizzles: n = (nl&3)*1024 + wb*4 + (nl>>2), 8 contiguous k
  if (t < 524288u) {
    const unsigned l   = (idx8 >> 3) & 63u;
    const unsigned kcw = (idx8 >> 9) & 31u;
    const unsigned wb  = idx8 >> 14;
    const unsigned nl  = l & 15u;
    const unsigned n   = (nl & 3u) * 1024u + wb * 4u + (nl >> 2);
    const unsigned k   = kcw * 32u + (l >> 4) * 8u;
    const float* wip = &Wih[n * 1024u + k];
    const float* whp = &Whh[n * 1024u + k];
    Pack8 pi, ph;
    #pragma unroll
    for (int e = 0; e < 8; ++e) { pi.o[e] = f2bf(wip[e]); ph.o[e] = f2bf(whp[e]); }
    *(u32x4*)&Wihp[idx8] = pi.v;
    *(u32x4*)&Whhp[idx8] = ph.v;
  }
  // mh slot 0 = bf16(h0 * mask_h); c init (fallback path)
  if (t < 8192u) {
    const unsigned l   = (idx8 >> 3) & 63u;
    const unsigned kwg = (idx8 >> 9) & 31u;
    const unsigned m   = idx8 >> 14;
    const unsigned b   = m * 16u + (l & 15u);
    const unsigned k   = kwg * 32u + (l >> 4) * 8u;
    const float* hp = &h0[b * 1024u + k];
    const float* mp = &mask_h[b * 1024u + k];
    Pack8 p;
    #pragma unroll
    for (int e = 0; e < 8; ++e) p.o[e] = f2bf(hp[e] * mp[e]);
    *(u32x4*)&mhp0[idx8] = p.v;
    *(f32x4*)&c[idx8]     = *(const f32x4*)&c0[idx8];
    *(f32x4*)&c[idx8 + 4] = *(const f32x4*)&c0[idx8 + 4];
  }
  if (t < 512u) {
    #pragma unroll
    for (int e = 0; e < 8; ++e) bias[idx8 + e] = bih[idx8 + e] + bhh[idx8 + e];
  }
}

// ---------------------------------------------------------------------------
// Persistent recurrence kernel: 256 blocks x 512 threads, all 256 steps.
// Block (rg = bk>>6, cg = bk&63) owns rows [rg*16, rg*16+16) x h-cols
// [cg*16, cg*16+16) (x4 gates). Wave w owns K-slice [w*128, (w+1)*128).
// No flags: each wave polls its own 4 mh fragments for the 0xFFFF sentinel.
// ---------------------------------------------------------------------------
__global__ __launch_bounds__(512) void lstm_persist(
    const u16* __restrict__ Ap, const u16* __restrict__ Wihp,
    const u16* __restrict__ Whhp, const float* __restrict__ bias,
    const float* __restrict__ c0, const float* __restrict__ mask_h,
    u16* __restrict__ mh_seq, float* __restrict__ out)
{
  __shared__ f32x4 lds[2][8][4][64];   // [parity][ww][nt][l] 64 KB dbuf

  const int tid = threadIdx.x;
  const int w   = tid >> 6;       // K-slice 0..7
  const int l   = tid & 63;
  const int bk  = blockIdx.x;
  const int rg  = bk >> 6;        // row-group 0..3 (16 batch rows)
  const int cg  = bk & 63;        // col-group 0..63 (16 h-cols)

  const bf16x8* WHV = (const bf16x8*)Whhp;
  const bf16x8* WIV = (const bf16x8*)Wihp;
  const bf16x8* ApV = (const bf16x8*)Ap;

  // Weights resident in registers for the whole sequence: 4 n-tiles x 4 kw.
  bf16x8 wh[4][4], wi[4][4];
  #pragma unroll
  for (int nt = 0; nt < 4; ++nt)
    #pragma unroll
    for (int kw = 0; kw < 4; ++kw) {
      wh[nt][kw] = WHV[((cg * 4 + nt) * 32 + w * 4 + kw) * 64 + l];
      wi[nt][kw] = WIV[((cg * 4 + nt) * 32 + w * 4 + kw) * 64 + l];
    }

  const int nl     = l & 15;
  const int quad   = l >> 4;
  const int g_role = nl & 3;
  const int jh     = nl >> 2;

  // Epilogue assignment: wave w handles n-tile (w&3), rows r in {rb, rb+1}.
  const int nt_e  = w & 3;
  const int rb    = (w >> 2) * 2;
  const int col_h = cg * 16 + nt_e * 4 + jh;
  const float bias_reg = bias[g_role * 1024 + col_h];
  float c_reg[2], mask_reg[2];
  #pragma unroll
  for (int rl = 0; rl < 2; ++rl) {
    const int row = rg * 16 + quad * 4 + rb + rl;
    c_reg[rl]    = c0[row * 1024 + col_h];
    mask_reg[rl] = mask_h[row * 1024 + col_h];
  }

  // mh store base (u16 units) for nl==0 lanes: fragment (m=rg, kwg=cg>>1),
  // l_t = ((cg&1)*2 + (nt_e>>1))*16 + row16, e = (nt_e&1)*4 + jh.
  const int mh_u16_base =
      ((rg * 32 + (cg >> 1)) * 64 + ((cg & 1) * 2 + (nt_e >> 1)) * 16 + quad * 4) * 8
      + (nt_e & 1) * 4;   // + (rb+rl)*8 per row

  __syncthreads();

  for (int s = 0; s < SEQ; ++s) {
    const u16* mi = mh_seq + (size_t)s * 65536;        // step-s input
    u16*       mo = mh_seq + (size_t)(s + 1) * 65536;  // step-s output
    const int  p  = s & 1;

    // ---- 1. issue this wave's 4 mh fragment loads (bypass). Their MALL
    // latency overlaps the x-projection; the first poll check is the wait.
    union { u32x4 r; bf16x8 v; } hf[4];
    #pragma unroll
    for (int kw = 0; kw < 4; ++kw) {
      const u32 off = (u32)(((rg * 32 + w * 4 + kw) * 64 + l) * 16);
      asm volatile("global_load_dwordx4 %0, %1, %2 sc0 sc1"
                   : "=v"(hf[kw].r) : "v"(off), "s"(mi) : "memory");
    }

    // ---- 2. x-projection (no cross-step dependency).
    f32x4 acc[4];
    #pragma unroll
    for (int nt = 0; nt < 4; ++nt) acc[nt] = (f32x4){0.f, 0.f, 0.f, 0.f};
    #pragma unroll
    for (int kw = 0; kw < 4; ++kw) {
      bf16x8 a = ApV[((s * 4 + rg) * 32 + w * 4 + kw) * 64 + l];
      #pragma unroll
      for (int nt = 0; nt < 4; ++nt)
        acc[nt] = __builtin_amdgcn_mfma_f32_16x16x32_bf16(a, wi[nt][kw], acc[nt], 0, 0, 0);
    }

    // ---- 3. data poll: the store IS the signal. u64 producer stores are
    // atomic => one u16 check per u64 (r[0] low half, r[2] low half).
    // Per-fragment re-issue; backoff after 8 rounds.
    {
      int spins = 0;
      for (;;) {
        asm volatile("s_waitcnt vmcnt(0)" ::: "memory");
        __builtin_amdgcn_sched_barrier(0);   // rule #18
        int b0 = ((hf[0].r[0] & 0xFFFFu) == 0xFFFFu) | ((hf[0].r[2] & 0xFFFFu) == 0xFFFFu);
        int b1 = ((hf[1].r[0] & 0xFFFFu) == 0xFFFFu) | ((hf[1].r[2] & 0xFFFFu) == 0xFFFFu);
        int b2 = ((hf[2].r[0] & 0xFFFFu) == 0xFFFFu) | ((hf[2].r[2] & 0xFFFFu) == 0xFFFFu);
        int b3 = ((hf[3].r[0] & 0xFFFFu) == 0xFFFFu) | ((hf[3].r[2] & 0xFFFFu) == 0xFFFFu);
        if (!__any(b0 | b1 | b2 | b3)) break;
        if (++spins > (1 << 14)) break;       // failsafe: never hang the queue
        if (spins > 8) __builtin_amdgcn_s_sleep(1);
        const int rebad[4] = { b0, b1, b2, b3 };
        #pragma unroll
        for (int kw = 0; kw < 4; ++kw) {
          if (__any(rebad[kw])) {             // wave-uniform re-issue
            const u32 off = (u32)(((rg * 32 + w * 4 + kw) * 64 + l) * 16);
            asm volatile("global_load_dwordx4 %0, %1, %2 sc0 sc1"
                         : "=v"(hf[kw].r) : "v"(off), "s"(mi) : "memory");
          }
        }
      }
      __builtin_amdgcn_sched_barrier(0);      // pin MFMAs after final check
    }

    // ---- 4. recurrent MFMAs (data already in registers from the poll).
    #pragma unroll
    for (int kw = 0; kw < 4; ++kw)
      #pragma unroll
      for (int nt = 0; nt < 4; ++nt)
        acc[nt] = __builtin_amdgcn_mfma_f32_16x16x32_bf16(hf[kw].v, wh[nt][kw], acc[nt], 0, 0, 0);

    #pragma unroll
    for (int nt = 0; nt < 4; ++nt) lds[p][w][nt][l] = acc[nt];
    __syncthreads();   // the ONLY barrier per step (LDS reduce readiness)

    // ---- 5. epilogue: wave w reduces n-tile nt_e, rows rb,rb+1. Stores are
    // fire-and-forget; their drain folds into next step's poll vmcnt(0).
    f32x4 t = lds[p][0][nt_e][l];
    #pragma unroll
    for (int ww = 1; ww < 8; ++ww) t += lds[p][ww][nt_e][l];

    f32x4 ho_s[2];
    f32x4 co_s[2];
    #pragma unroll
    for (int rl = 0; rl < 2; ++rl) {
      const int r = rb + rl;
      const float gp = t[r] + bias_reg;
      const float v1 = __shfl_xor(gp, 1, 64);
      const float v2 = __shfl_xor(gp, 2, 64);
      const float v3 = __shfl_xor(gp, 3, 64);
      const float ig = pick4(g_role,     gp, v1, v2, v3);
      const float fg = pick4(g_role ^ 1, gp, v1, v2, v3);
      const float gg = pick4(g_role ^ 2, gp, v1, v2, v3);
      const float og = pick4(g_role ^ 3, gp, v1, v2, v3);
      const float iv = sigm(ig);
      const float fv = sigm(fg);
      const float gv = tanh_fast(gg);
      const float ov = sigm(og);
      const float cn = fv * c_reg[rl] + iv * gv;
      c_reg[rl] = cn;
      const float hn = ov * tanh_fast(cn);
      const float mv = hn * mask_reg[rl];

      // gather the n-tile's 4 h-cols (jh) into the nl==0 lanes
      const float h1 = __shfl_xor(hn, 4, 64);
      const float h2 = __shfl_xor(hn, 8, 64);
      const float h3 = __shfl_xor(hn, 12, 64);
      const float m1 = __shfl_xor(mv, 4, 64);
      const float m2 = __shfl_xor(mv, 8, 64);
      const float m3 = __shfl_xor(mv, 12, 64);
      ho_s[rl] = (f32x4){hn, h1, h2, h3};
      if (s == SEQ - 1) {
        const float cn1 = __shfl_xor(cn, 4, 64);
        const float cn2 = __shfl_xor(cn, 8, 64);
        const float cn3 = __shfl_xor(cn, 12, 64);
        co_s[rl] = (f32x4){cn, cn1, cn2, cn3};
      }
      if (nl == 0) {
        // The store IS the signal: atomic u64, write-through to the MALL.
        const u64 pk = (u64)f2bf(mv) | ((u64)f2bf(m1) << 16)
                     | ((u64)f2bf(m2) << 32) | ((u64)f2bf(m3) << 48);
        __hip_atomic_store((u64*)&mo[mh_u16_base + r * 8], pk,
                           __ATOMIC_RELAXED, __HIP_MEMORY_SCOPE_AGENT);
      }
    }
    if (nl == 0) {
      #pragma unroll
      for (int rl = 0; rl < 2; ++rl) {
        const int row = rg * 16 + quad * 4 + rb + rl;
        *(f32x4*)&out[((size_t)s * 64 + row) * 1024 + cg * 16 + nt_e * 4] = ho_s[rl];
        if (s == SEQ - 1) {
          *(f32x4*)&out[16777216 + row * 1024 + cg * 16 + nt_e * 4] = ho_s[rl];         // h_n
          *(f32x4*)&out[16777216 + 65536 + row * 1024 + cg * 16 + nt_e * 4] = co_s[rl]; // c_n
        }
      }
    }
    // no barrier #2: LDS is double-buffered; barrier #1 bounds skew to 1 step.
  }
}

// ---------------------------------------------------------------------------
// Fallback per-step kernel (R3, unchanged): used only when ws is too small.
// ---------------------------------------------------------------------------
__global__ __launch_bounds__(256) void lstm_step(
    const u16* __restrict__ Ap,
    const u16* __restrict__ Wihp,
    const u16* __restrict__ Whhp,
    const _Float16* __restrict__ xg,  // null => fold x-GEMM
    const float* __restrict__ bias,
    const u16* __restrict__ mh_in, u16* __restrict__ mh_out,
    float* __restrict__ c, const float* __restrict__ mask_h,
    float* __restrict__ out, int s)
{
  __shared__ f32x4 lds[4][4][64];   // [w][m][l] 16 KB

  const int tid = threadIdx.x;
  const int w   = tid >> 6;      // K-slice
  const int l   = tid & 63;
  const int bk  = blockIdx.x;    // 4 h-cols

  const bf16x8* mb = (const bf16x8*)mh_in;
  const bf16x8* WH = (const bf16x8*)Whhp;

  f32x4 acc[4] = { {0,0,0,0}, {0,0,0,0}, {0,0,0,0}, {0,0,0,0} };

  #pragma unroll 2
  for (int kw = 0; kw < 8; ++kw) {
    bf16x8 b = WH[(bk * 32 + w * 8 + kw) * 64 + l];
    #pragma unroll
    for (int m = 0; m < 4; ++m) {
      bf16x8 a = mb[(m * 32 + w * 8 + kw) * 64 + l];
      acc[m] = __builtin_amdgcn_mfma_f32_16x16x32_bf16(a, b, acc[m], 0, 0, 0);
    }
  }
  if (xg == nullptr) {   // fold x-projection
    const bf16x8* ApV = (const bf16x8*)Ap;
    const bf16x8* WI  = (const bf16x8*)Wihp;
    #pragma unroll 2
    for (int kw = 0; kw < 8; ++kw) {
      bf16x8 b = WI[(bk * 32 + w * 8 + kw) * 64 + l];
      #pragma unroll
      for (int m = 0; m < 4; ++m) {
        bf16x8 a = ApV[((s * 4 + m) * 32 + w * 8 + kw) * 64 + l];
        acc[m] = __builtin_amdgcn_mfma_f32_16x16x32_bf16(a, b, acc[m], 0, 0, 0);
      }
    }
  }
  #pragma unroll
  for (int m = 0; m < 4; ++m) lds[w][m][l] = acc[m];
  __syncthreads();

  f32x4 t = lds[0][w][l];
  #pragma unroll
  for (int ww = 1; ww < 4; ++ww) t += lds[ww][w][l];

  const int nl     = l & 15;
  const int quad   = l >> 4;
  const int g_role = nl & 3;
  const int jh     = nl >> 2;
  const int col_h  = bk * 4 + jh;

  if (xg != nullptr) {
    f16x4 xv = *(const f16x4*)&xg[((((size_t)s * 256 + bk) * 4 + w) * 64 + l) * 4];
    #pragma unroll
    for (int r = 0; r < 4; ++r) t[r] += (float)xv[r];
  }
  const float bias_reg = bias[g_role * 1024 + col_h];
  const int kwg = col_h >> 5;
  const int lp  = ((col_h >> 3) & 3) * 16;

  #pragma unroll
  for (int r = 0; r < 4; ++r) {
    const int b_row = w * 16 + quad * 4 + r;
    const float gp = t[r] + bias_reg;
    const float v1 = __shfl_xor(gp, 1, 64);
    const float v2 = __shfl_xor(gp, 2, 64);
    const float v3 = __shfl_xor(gp, 3, 64);
    const float ig = pick4(g_role,     gp, v1, v2, v3);
    const float fg = pick4(g_role ^ 1, gp, v1, v2, v3);
    const float gg = pick4(g_role ^ 2, gp, v1, v2, v3);
    const float og = pick4(g_role ^ 3, gp, v1, v2, v3);
    const float iv = sigm(ig);
    const float fv = sigm(fg);
    const float gv = tanh_fast(gg);
    const float ov = sigm(og);
    const float cold = c[b_row * 1024 + col_h];
    const float cn = fv * cold + iv * gv;
    const float hn = ov * tanh_fast(cn);
    if (g_role == 0) {
      c[b_row * 1024 + col_h] = cn;
      out[((size_t)s * 64 + b_row) * 1024 + col_h] = hn;
      mh_out[((w * 32 + kwg) * 64 + (lp + (b_row & 15))) * 8 + (col_h & 7)] =
          f2bf(hn * mask_h[b_row * 1024 + col_h]);
      if (s == SEQ - 1) {
        out[16777216 + b_row * 1024 + col_h] = hn;           // h_n
        out[16777216 + 65536 + b_row * 1024 + col_h] = cn;   // c_n
      }
    }
  }
}

extern "C" void kernel_launch(void* const* d_in, const int* in_sizes, int n_in,
                              void* d_out, int out_size, void* d_ws, size_t ws_size,
                              hipStream_t stream)
{
  const float* x      = (const float*)d_in[0];
  const float* h0     = (const float*)d_in[1];
  const float* c0     = (const float*)d_in[2];
  const float* mask_x = (const float*)d_in[3];
  const float* mask_h = (const float*)d_in[4];
  const float* Wih    = (const float*)d_in[5];
  const float* Whh    = (const float*)d_in[6];
  const float* bih    = (const float*)d_in[7];
  const float* bhh    = (const float*)d_in[8];
  float* out = (float*)d_out;

  char* ws = (char*)d_ws;
  u16*   Wihp   = (u16*)(ws + 0);
  u16*   Whhp   = (u16*)(ws + 8388608);
  u16*   Ap     = (u16*)(ws + 16777216);
  u16*   mh0    = (u16*)(ws + 50331648);
  u16*   mh1    = (u16*)(ws + 50462720);
  float* bias   = (float*)(ws + 50593792);
  float* c      = (float*)(ws + 50610176);
  u16*   mh_seq = (u16*)(ws + 50873344);   // 257 x 131072 B, end 84558848
  const bool persist = (ws_size >= (size_t)84558848);

  u16* mh_init = persist ? mh_seq : mh0;   // prep writes the step-0 mh here

  hipLaunchKernelGGL(prep_kernel, dim3(8192), dim3(256), 0, stream,
                     x, h0, c0, mask_x, mask_h, Wih, Whh, bih, bhh,
                     Wihp, Whhp, Ap, mh_init, bias, c, mh_seq, (int)persist);

  if (persist) {
    hipLaunchKernelGGL(lstm_persist, dim3(256), dim3(512), 0, stream,
                       Ap, Wihp, Whhp, bias, c0, mask_h, mh_seq, out);
  } else {
    for (int s = 0; s < SEQ; ++s) {
      const u16* mi = (s & 1) ? mh1 : mh0;
      u16*       mo = (s & 1) ? mh0 : mh1;
      hipLaunchKernelGGL(lstm_step, dim3(256), dim3(256), 0, stream,
                         Ap, Wihp, Whhp, (const _Float16*)nullptr, bias, mi, mo,
                         c, mask_h, out, s);
    }
  }
}